// Round 7
// baseline (438.842 us; speedup 1.0000x reference)
//
#include <hip/hip_runtime.h>
#include <math.h>

#define K_TOT 32
#define K_IND 16
#define K_MLP 16
#define DHID  64
#define EB    512          // edges per block in edge_kernel
#define CAP   96           // max receiver span per block (LDS rows)
#define ROWS  68           // padded row stride (floats) to spread LDS banks

// ------------------------------------------------------------------
// Prep: block 0 wave 0 computes collapsed-MLP constants
//   P_k = sum_{j: w1_j>0} w1_j*w2[j][k], N_k = sum_{j: w1_j<0} w1_j*w2[j][k]
// and flag = (all b1 == 0). All threads t<=N: rp[t] = lower_bound(recv, t).
__global__ void prep_kernel(const int* __restrict__ recv, int E, int N,
                            const float* __restrict__ w1,
                            const float* __restrict__ b1,
                            const float* __restrict__ w2,
                            float* __restrict__ wsP,
                            float* __restrict__ wsN,
                            int* __restrict__ wsflag,
                            int* __restrict__ rp) {
    if (blockIdx.x == 0 && threadIdx.x < 64) {
        int t = threadIdx.x;
        if (t < K_MLP) {
            float P = 0.f, Nn = 0.f;
            for (int j = 0; j < DHID; ++j) {
                float w = w1[j];
                float v = w2[j * K_MLP + t];
                P  += fmaxf(w, 0.f) * v;
                Nn += fminf(w, 0.f) * v;
            }
            wsP[t] = P; wsN[t] = Nn;
        }
        bool nz = (b1[t] != 0.f);
        unsigned long long mask = __ballot(nz);
        if (t == 0) *wsflag = (mask == 0ull) ? 1 : 0;
    }
    int tid = blockIdx.x * blockDim.x + threadIdx.x;
    if (tid <= N) {
        int lo = 0, hi = E;
        while (lo < hi) {
            int mid = (lo + hi) >> 1;
            if (recv[mid] < tid) lo = mid + 1; else hi = mid;
        }
        rp[tid] = lo;
    }
}

// ------------------------------------------------------------------
// Edge-parallel accumulate. Block owns EB contiguous edges (receivers sorted
// => span ~ EB/16 +1 nodes). LDS table lds[row][slot], slot layout:
//   [0,16) cnt per bin, [16,32) sum pe*pd per bin,
//   [32,48) sum p per mlp ch, [48,64) sum p*pe*pd per mlp ch.
// Softmax p = exp(d*q_k - |q_k|*DIST_MAX): channel-constant shift, cancels
// exactly in the softmax ratio. Interior receivers are block-exclusive ->
// plain global store; boundary receivers -> atomicAdd. Span>CAP (never in
// practice) -> per-edge global atomics.
__global__ __launch_bounds__(256) void edge_kernel(
        const float* __restrict__ nodes,
        const float* __restrict__ dist,
        const float* __restrict__ padv,
        const int*   __restrict__ send,
        const int*   __restrict__ recv,
        const float* __restrict__ a_p,
        const float* __restrict__ b_p,
        const float* __restrict__ wsP,
        const float* __restrict__ wsN,
        const int*   __restrict__ wsflag,
        float* __restrict__ gacc,
        int E) {
    bool fastf = (*wsflag != 0) && (fabsf(b_p[0]) == 2.0f);
    if (!fastf) return;   // generic inputs handled entirely in node_kernel

    __shared__ float lds[CAP * ROWS];
    int tid = threadIdx.x;
    int e0 = blockIdx.x * EB;
    int eEnd = e0 + EB; if (eEnd > E) eEnd = E;

    // zero LDS
    for (int i = tid; i < (CAP * ROWS) / 4; i += 256)
        ((float4*)lds)[i] = make_float4(0.f, 0.f, 0.f, 0.f);

    int rFirst = recv[e0];
    int rLast  = recv[eEnd - 1];
    int span = rLast - rFirst + 1;
    bool overflow = span > CAP;
    __syncthreads();

    int lane = tid & 63;
    int wid  = tid >> 6;
    int esub = lane >> 4;     // 4 edge slots
    int cc   = lane & 15;     // channel pair: indicator cc, mlp cc+16

    float a_c = fminf(fmaxf(a_p[0], 0.f), 1.f);
    float am  = 1.f - a_c;
    float Pk  = wsP[cc];
    float Nk  = wsN[cc];
    float negM = -fmaxf(fabsf(Pk), fabsf(Nk));   // * DIST_MAX (=1, baked into bins)
    float lo = (float)cc * 0.0625f;
    float hi = lo + 0.0625f;

    int wbeg = e0 + wid * 128;
    int wend = wbeg + 128; if (wend > eEnd) wend = eEnd;

    if (!overflow) {
        for (int e = wbeg + esub; e < wend; e += 4) {
            float d  = dist[e];
            int   s  = send[e];
            float pe = padv[e];
            int   r  = recv[e];
            float* row = lds + (r - rFirst) * ROWS;
            const float* nsr = nodes + (s * K_TOT + cc);
            float ns0 = nsr[0], ns1 = nsr[16];
            const float* nrr = nodes + (r * K_TOT + cc);
            float nr0 = nrr[0], nr1 = nrr[16];
            float t0 = fmaf(a_c, nr0, -(am * ns0));
            float t1 = fmaf(a_c, nr1, -(am * ns1));
            float pd0 = t0 * t0, pd1 = t1 * t1;
            if ((d > lo) && (d < hi)) {
                atomicAdd(row + cc, 1.f);
                atomicAdd(row + cc + 16, pe * pd0);
            }
            float q = (d > 0.f) ? Pk : Nk;
            float p = __expf(fmaf(d, q, negM));
            atomicAdd(row + cc + 32, p);
            atomicAdd(row + cc + 48, p * (pe * pd1));
        }
    } else {
        for (int e = wbeg + esub; e < wend; e += 4) {
            float d  = dist[e];
            int   s  = send[e];
            float pe = padv[e];
            int   r  = recv[e];
            float* row = gacc + (size_t)r * 64;
            const float* nsr = nodes + (s * K_TOT + cc);
            float ns0 = nsr[0], ns1 = nsr[16];
            const float* nrr = nodes + (r * K_TOT + cc);
            float nr0 = nrr[0], nr1 = nrr[16];
            float t0 = fmaf(a_c, nr0, -(am * ns0));
            float t1 = fmaf(a_c, nr1, -(am * ns1));
            float pd0 = t0 * t0, pd1 = t1 * t1;
            if ((d > lo) && (d < hi)) {
                atomicAdd(row + cc, 1.f);
                atomicAdd(row + cc + 16, pe * pd0);
            }
            float q = (d > 0.f) ? Pk : Nk;
            float p = __expf(fmaf(d, q, negM));
            atomicAdd(row + cc + 32, p);
            atomicAdd(row + cc + 48, p * (pe * pd1));
        }
    }
    __syncthreads();

    if (!overflow) {
        // flush: interior receivers exclusive to this block -> store;
        // boundary (rFirst, rLast) shared with neighbor blocks -> atomicAdd.
        int total = span * 64;
        for (int i = tid; i < total; i += 256) {
            int rl = i >> 6;
            int slot = i & 63;
            float v = lds[rl * ROWS + slot];
            int r = rFirst + rl;
            float* dst = gacc + (size_t)r * 64 + slot;
            if (r == rFirst || r == rLast) atomicAdd(dst, v);
            else *dst = v;
        }
    }
}

// ------------------------------------------------------------------
// Node-parallel finalize + fused epilogue. Wave handles 2 nodes:
// p = lane>>5 selects node, c = lane&31 the channel.
// Fast path: read 64-float accum row (256B coalesced), finalize g.
// Generic path: full R6 per-node recompute (powf + MLP + online softmax).
__global__ __launch_bounds__(256) void node_kernel(
        const float* __restrict__ nodes,
        const float* __restrict__ gacc,
        const float* __restrict__ wg_self,
        const float* __restrict__ wg_gath,
        const float* __restrict__ bg,
        float* __restrict__ out,
        int N,
        // generic-path inputs:
        const float* __restrict__ dist,
        const float* __restrict__ padv,
        const int*   __restrict__ send,
        const int*   __restrict__ rp,
        const float* __restrict__ w1,
        const float* __restrict__ b1,
        const float* __restrict__ w2,
        const float* __restrict__ a_p,
        const float* __restrict__ b_p,
        const int*   __restrict__ wsflag) {
    int wave = blockIdx.x * 4 + (threadIdx.x >> 6);
    int lane = threadIdx.x & 63;
    int n0 = wave * 2;
    if (n0 >= N) return;
    int p = lane >> 5;
    int c = lane & 31;
    int node = n0 + p;
    int nld = node < N ? node : N - 1;

    bool fastf = (*wsflag != 0) && (fabsf(b_p[0]) == 2.0f);
    float pre_g, pre_n;

    if (__builtin_amdgcn_readfirstlane((int)fastf)) {
        const float* row = gacc + (size_t)nld * 64;
        int s1 = (c < 16) ? c : c + 16;
        float v1 = row[s1];         // cnt or l
        float v2 = row[s1 + 16];    // si  or acc
        pre_g = (c < 16) ? v2 / (v1 + 1e-5f)
                         : ((v1 > 0.f) ? v2 / v1 : 0.f);
        pre_n = nodes[nld * K_TOT + c];
    } else {
        // -------- generic fallback: R6 slow path per node --------
        float a_c = fminf(fmaxf(a_p[0], 0.f), 1.f);
        float am  = 1.f - a_c;
        float bc  = fabsf(b_p[0]);
        int eg = lane >> 4, cc = lane & 15;
        float lo = (float)cc * 0.0625f;
        float hi = lo + 0.0625f;
        float gi0 = 0.f, gm0 = 0.f, gi1 = 0.f, gm1 = 0.f;
        for (int t = 0; t < 2; ++t) {
            int nn = n0 + t;
            float g_ind = 0.f, g_mlp = 0.f;
            if (nn < N) {
                const float* nrow = nodes + nn * K_TOT;
                float nr0 = nrow[cc], nr1 = nrow[cc + 16];
                float anr0 = a_c * nr0, anr1 = a_c * nr1;
                int e0 = rp[nn], eEnd = rp[nn + 1];
                float cnt = 0.f, si = 0.f, l = 0.f, acc = 0.f, m_on = -INFINITY;
                for (int i = e0 + eg; i < eEnd; i += 4) {
                    float d  = dist[i];
                    int   s  = send[i];
                    float pe = padv[i];
                    const float* nsr = nodes + (s * K_TOT + cc);
                    float ns0 = nsr[0], ns1 = nsr[16];
                    float t0 = fabsf(fmaf(-am, ns0, anr0));
                    float t1 = fabsf(fmaf(-am, ns1, anr1));
                    float pd0 = powf(t0, bc);
                    float pd1 = powf(t1, bc);
                    bool inb = (d > lo) && (d < hi);
                    cnt += inb ? 1.f : 0.f;
                    si  += inb ? pe * pd0 : 0.f;
                    float mlp = 0.f;   // b2 cancels in the softmax ratio
                    for (int j = 0; j < DHID; ++j) {
                        float h = fmaxf(fmaf(d, w1[j], b1[j]), 0.f);
                        mlp = fmaf(h, w2[j * K_MLP + cc], mlp);
                    }
                    float mn = fmaxf(m_on, mlp);
                    float al = (m_on == -INFINITY) ? 0.f : __expf(m_on - mn);
                    float pp = __expf(mlp - mn);
                    l   = fmaf(l, al, pp);
                    acc = fmaf(acc, al, pp * pe * pd1);
                    m_on = mn;
                }
#pragma unroll
                for (int off = 16; off <= 32; off <<= 1) {
                    cnt += __shfl_xor(cnt, off);
                    si  += __shfl_xor(si,  off);
                    float m2 = __shfl_xor(m_on, off), l2 = __shfl_xor(l, off), a2 = __shfl_xor(acc, off);
                    float mn = fmaxf(m_on, m2);
                    float f1 = (m_on == -INFINITY) ? 0.f : __expf(m_on - mn);
                    float f2 = (m2   == -INFINITY) ? 0.f : __expf(m2 - mn);
                    l   = l * f1 + l2 * f2;
                    acc = acc * f1 + a2 * f2;
                    m_on = mn;
                }
                g_ind = si / (cnt + 1e-5f);
                g_mlp = (l > 0.f) ? (acc / l) : 0.f;
            }
            if (t == 0) { gi0 = g_ind; gm0 = g_mlp; }
            else        { gi1 = g_ind; gm1 = g_mlp; }
        }
        int srcl = c & 15;
        float si0 = __shfl(gi0, srcl), si1 = __shfl(gi1, srcl);
        float sm0 = __shfl(gm0, srcl), sm1 = __shfl(gm1, srcl);
        float sgi = p ? si1 : si0;
        float sgm = p ? sm1 : sm0;
        pre_g = (c < 16) ? sgi : sgm;
        pre_n = nodes[nld * K_TOT + c];
    }

    // fused epilogue: out[node][c] = relu(sum_j nr_j*Ws[j][c] + g_j*Wg[j][c] + bg[c])
    float o = 0.f;
    int sbase = p << 5;
#pragma unroll
    for (int j = 0; j < 32; ++j) {
        float gj = __shfl(pre_g, sbase + j);
        float nj = __shfl(pre_n, sbase + j);
        o = fmaf(nj, wg_self[j * K_TOT + c], o);
        o = fmaf(gj, wg_gath[j * K_TOT + c], o);
    }
    if (node < N) out[node * K_TOT + c] = fmaxf(o + bg[c], 0.f);
}

// ------------------------------------------------------------------
// Fallback single-kernel path (R6, proven) for when ws_size is too small
// to hold the 25.6MB accumulator.
__global__ __launch_bounds__(256) void graph_kernel_fb(
        const float* __restrict__ nodes,
        const float* __restrict__ dist,
        const float* __restrict__ padv,
        const int*   __restrict__ send,
        const float* __restrict__ w1,
        const float* __restrict__ b1,
        const float* __restrict__ w2,
        const float* __restrict__ a_p,
        const float* __restrict__ b_p,
        const float* __restrict__ wg_self,
        const float* __restrict__ wg_gath,
        const float* __restrict__ bg,
        const float* __restrict__ wsP,
        const float* __restrict__ wsN,
        const int*   __restrict__ wsflag,
        const int*   __restrict__ rp,
        float* __restrict__ out,
        int N) {
    int wave = blockIdx.x * (blockDim.x >> 6) + (threadIdx.x >> 6);
    if (wave >= N) return;
    int n    = wave;
    int lane = threadIdx.x & 63;
    int eg   = lane >> 4;
    int cc   = lane & 15;

    float a_c = fminf(fmaxf(a_p[0], 0.f), 1.f);
    float am  = 1.f - a_c;
    float bc  = fabsf(b_p[0]);
    float Pk = wsP[cc];
    float Nk = wsN[cc];
    const float* nrow = nodes + n * K_TOT;
    float nr0 = nrow[cc];
    float nr1 = nrow[cc + 16];
    float anr0 = a_c * nr0, anr1 = a_c * nr1;
    int e0 = rp[n], eEnd = rp[n + 1];
    int len = eEnd - e0;
    float lo = (float)cc * 0.0625f;
    float hi = lo + 0.0625f;
    float cnt = 0.f, si = 0.f, l = 0.f, acc = 0.f;
    float g_ind, g_mlp;
    bool fastf = (*wsflag != 0) && (bc == 2.0f) && (len <= 64);

    if (__builtin_amdgcn_readfirstlane((int)fastf)) {
        if (len > 0) {
            int idx = lane < len ? lane : len - 1;
            float dm = fabsf(dist[e0 + idx]);
#pragma unroll
            for (int off = 32; off; off >>= 1) dm = fmaxf(dm, __shfl_xor(dm, off));
            float negM = -fmaxf(fabsf(Pk), fabsf(Nk)) * dm;
            int nG = (len + 3) >> 2;
            int last = len - 1;
            for (int g = 0; g < nG; ++g) {
                int i = (g << 2) + eg;
                bool valid = i < len;
                int ii = valid ? i : last;
                float d  = dist[e0 + ii];
                int   s  = send[e0 + ii];
                float pe = padv[e0 + ii];
                const float* nsr = nodes + (s * K_TOT + cc);
                float ns0 = nsr[0], ns1 = nsr[16];
                float t0 = fmaf(-am, ns0, anr0);
                float t1 = fmaf(-am, ns1, anr1);
                float pd0 = t0 * t0, pd1 = t1 * t1;
                bool inb = valid && (d > lo) && (d < hi);
                cnt += inb ? 1.f : 0.f;
                si   = inb ? fmaf(pe, pd0, si) : si;
                float q = (d > 0.f) ? Pk : Nk;
                float pp = __expf(fmaf(d, q, negM));
                pp = valid ? pp : 0.f;
                l += pp;
                acc = fmaf(pp, pe * pd1, acc);
            }
        }
#pragma unroll
        for (int off = 16; off <= 32; off <<= 1) {
            cnt += __shfl_xor(cnt, off);
            si  += __shfl_xor(si,  off);
            l   += __shfl_xor(l,   off);
            acc += __shfl_xor(acc, off);
        }
        g_ind = si / (cnt + 1e-5f);
        g_mlp = (l > 0.f) ? (acc / l) : 0.f;
    } else {
        float m_on = -INFINITY;
        for (int i = eg; i < len; i += 4) {
            int e = e0 + i;
            float d  = dist[e];
            int   s  = send[e];
            float pe = padv[e];
            const float* nsr = nodes + (s * K_TOT + cc);
            float ns0 = nsr[0], ns1 = nsr[16];
            float t0 = fabsf(fmaf(-am, ns0, anr0));
            float t1 = fabsf(fmaf(-am, ns1, anr1));
            float pd0 = powf(t0, bc), pd1 = powf(t1, bc);
            bool inb = (d > lo) && (d < hi);
            cnt += inb ? 1.f : 0.f;
            si  += inb ? pe * pd0 : 0.f;
            float mlp = 0.f;
            for (int j = 0; j < DHID; ++j) {
                float h = fmaxf(fmaf(d, w1[j], b1[j]), 0.f);
                mlp = fmaf(h, w2[j * K_MLP + cc], mlp);
            }
            float mn = fmaxf(m_on, mlp);
            float al = (m_on == -INFINITY) ? 0.f : __expf(m_on - mn);
            float pp = __expf(mlp - mn);
            l   = fmaf(l, al, pp);
            acc = fmaf(acc, al, pp * pe * pd1);
            m_on = mn;
        }
#pragma unroll
        for (int off = 16; off <= 32; off <<= 1) {
            cnt += __shfl_xor(cnt, off);
            si  += __shfl_xor(si,  off);
            float m2 = __shfl_xor(m_on, off), l2 = __shfl_xor(l, off), a2 = __shfl_xor(acc, off);
            float mn = fmaxf(m_on, m2);
            float f1 = (m_on == -INFINITY) ? 0.f : __expf(m_on - mn);
            float f2 = (m2   == -INFINITY) ? 0.f : __expf(m2 - mn);
            l   = l * f1 + l2 * f2;
            acc = acc * f1 + a2 * f2;
            m_on = mn;
        }
        g_ind = si / (cnt + 1e-5f);
        g_mlp = (l > 0.f) ? (acc / l) : 0.f;
    }

    int h  = lane >> 5;
    int oc = lane & 31;
    float pre_g = ((lane >> 4) & 1) ? g_mlp : g_ind;
    float pre_n = ((lane >> 4) & 1) ? nr1 : nr0;
    float o_s = 0.f, o_g = 0.f;
    int jbase = h * 16;
#pragma unroll
    for (int jj = 0; jj < 16; ++jj) {
        int j = jbase + jj;
        float gj = __shfl(pre_g, j);
        float nj = __shfl(pre_n, j);
        o_s = fmaf(nj, wg_self[j * K_TOT + oc], o_s);
        o_g = fmaf(gj, wg_gath[j * K_TOT + oc], o_g);
    }
    float o = o_s + o_g;
    o += __shfl_xor(o, 32);
    if (h == 0) {
        out[n * K_TOT + oc] = fmaxf(o + bg[oc], 0.f);
    }
}

// ------------------------------------------------------------------
extern "C" void kernel_launch(void* const* d_in, const int* in_sizes, int n_in,
                              void* d_out, int out_size, void* d_ws, size_t ws_size,
                              hipStream_t stream) {
    const float* nodes   = (const float*)d_in[0];
    const float* dist    = (const float*)d_in[1];
    const float* padv    = (const float*)d_in[2];
    const int*   recv    = (const int*)d_in[3];
    const int*   send    = (const int*)d_in[4];
    const float* w1      = (const float*)d_in[5];
    const float* b1      = (const float*)d_in[6];
    const float* w2      = (const float*)d_in[7];
    const float* a_p     = (const float*)d_in[9];
    const float* b_p     = (const float*)d_in[10];
    const float* wg_self = (const float*)d_in[11];
    const float* wg_gath = (const float*)d_in[12];
    const float* bg      = (const float*)d_in[13];
    float* out = (float*)d_out;

    int N = in_sizes[0] / K_TOT;
    int E = in_sizes[1];

    size_t gacc_elems = (size_t)N * 64;
    size_t need = (gacc_elems + 64 + (size_t)N + 1 + 64) * sizeof(float);

    if (ws_size >= need) {
        // ---- fast 4-dispatch path ----
        float* gacc   = (float*)d_ws;
        float* meta   = gacc + gacc_elems;
        float* wsP    = meta;
        float* wsN    = meta + 16;
        int*   wsflag = (int*)(meta + 32);
        int*   rp     = (int*)(meta + 64);

        prep_kernel<<<(N + 1 + 255) / 256, 256, 0, stream>>>(
            recv, E, N, w1, b1, w2, wsP, wsN, wsflag, rp);
        hipMemsetAsync(gacc, 0, gacc_elems * sizeof(float), stream);
        edge_kernel<<<(E + EB - 1) / EB, 256, 0, stream>>>(
            nodes, dist, padv, send, recv, a_p, b_p, wsP, wsN, wsflag, gacc, E);
        int nwaves = (N + 1) / 2;
        node_kernel<<<(nwaves + 3) / 4, 256, 0, stream>>>(
            nodes, gacc, wg_self, wg_gath, bg, out, N,
            dist, padv, send, rp, w1, b1, w2, a_p, b_p, wsflag);
    } else {
        // ---- fallback: proven single-kernel path (R6) ----
        float* wsf    = (float*)d_ws;
        float* wsP    = wsf;
        float* wsN    = wsf + 16;
        int*   wsflag = (int*)d_ws + 32;
        int*   rp     = (int*)d_ws + 64;

        prep_kernel<<<(N + 1 + 255) / 256, 256, 0, stream>>>(
            recv, E, N, w1, b1, w2, wsP, wsN, wsflag, rp);
        graph_kernel_fb<<<(N + 3) / 4, 256, 0, stream>>>(
            nodes, dist, padv, send, w1, b1, w2, a_p, b_p,
            wg_self, wg_gath, bg, wsP, wsN, wsflag, rp, out, N);
    }
}

// Round 8
// 438.222 us; speedup vs baseline: 1.0014x; 1.0014x over previous
//
#include <hip/hip_runtime.h>
#include <math.h>

#define K_TOT 32
#define K_IND 16
#define K_MLP 16
#define DHID  64
#define EB    512          // edges per block in edge_kernel
#define CAP   96           // max receiver span per block (LDS rows)
#define ROWS  68           // padded row stride (floats) to spread LDS banks

// ------------------------------------------------------------------
// Prep: block 0 wave 0 computes collapsed-MLP constants
//   P_k = sum_{j: w1_j>0} w1_j*w2[j][k], N_k = sum_{j: w1_j<0} w1_j*w2[j][k]
// and flag = (all b1 == 0). All threads t<=N: rp[t] = lower_bound(recv, t).
__global__ void prep_kernel(const int* __restrict__ recv, int E, int N,
                            const float* __restrict__ w1,
                            const float* __restrict__ b1,
                            const float* __restrict__ w2,
                            float* __restrict__ wsP,
                            float* __restrict__ wsN,
                            int* __restrict__ wsflag,
                            int* __restrict__ rp) {
    if (blockIdx.x == 0 && threadIdx.x < 64) {
        int t = threadIdx.x;
        if (t < K_MLP) {
            float P = 0.f, Nn = 0.f;
            for (int j = 0; j < DHID; ++j) {
                float w = w1[j];
                float v = w2[j * K_MLP + t];
                P  += fmaxf(w, 0.f) * v;
                Nn += fminf(w, 0.f) * v;
            }
            wsP[t] = P; wsN[t] = Nn;
        }
        bool nz = (b1[t] != 0.f);
        unsigned long long mask = __ballot(nz);
        if (t == 0) *wsflag = (mask == 0ull) ? 1 : 0;
    }
    int tid = blockIdx.x * blockDim.x + threadIdx.x;
    if (tid <= N) {
        int lo = 0, hi = E;
        while (lo < hi) {
            int mid = (lo + hi) >> 1;
            if (recv[mid] < tid) lo = mid + 1; else hi = mid;
        }
        rp[tid] = lo;
    }
}

// ------------------------------------------------------------------
// Edge-parallel accumulate. Block owns EB contiguous edges (receivers sorted
// => span ~ EB/16 +1 nodes). LDS table lds[row][slot], slot layout:
//   [0,16) cnt per bin, [16,32) sum pe*pd per bin,
//   [32,48) sum p per mlp ch, [48,64) sum p*pe*pd per mlp ch.
// Softmax p = exp(d*q_k - |q_k|*DIST_MAX): channel-constant shift, cancels
// exactly in the softmax ratio. All fp32 accumulation uses unsafeAtomicAdd
// -> native ds_add_f32 / global_atomic_add_f32 (plain atomicAdd(float*)
// compiles to a CAS retry loop on gfx950: R7 measured 300us, VALUBusy 7.7%).
// Interior receivers are block-exclusive -> plain global store; boundary
// receivers -> global atomic. Span>CAP (never in practice) -> per-edge
// global atomics.
__global__ __launch_bounds__(256) void edge_kernel(
        const float* __restrict__ nodes,
        const float* __restrict__ dist,
        const float* __restrict__ padv,
        const int*   __restrict__ send,
        const int*   __restrict__ recv,
        const float* __restrict__ a_p,
        const float* __restrict__ b_p,
        const float* __restrict__ wsP,
        const float* __restrict__ wsN,
        const int*   __restrict__ wsflag,
        float* __restrict__ gacc,
        int E) {
    bool fastf = (*wsflag != 0) && (fabsf(b_p[0]) == 2.0f);
    if (!fastf) return;   // generic inputs handled entirely in node_kernel

    __shared__ float lds[CAP * ROWS];
    int tid = threadIdx.x;
    int e0 = blockIdx.x * EB;
    int eEnd = e0 + EB; if (eEnd > E) eEnd = E;

    // zero LDS
    for (int i = tid; i < (CAP * ROWS) / 4; i += 256)
        ((float4*)lds)[i] = make_float4(0.f, 0.f, 0.f, 0.f);

    int rFirst = recv[e0];
    int rLast  = recv[eEnd - 1];
    int span = rLast - rFirst + 1;
    bool overflow = span > CAP;
    __syncthreads();

    int lane = tid & 63;
    int wid  = tid >> 6;
    int esub = lane >> 4;     // 4 edge slots
    int cc   = lane & 15;     // channel pair: indicator cc, mlp cc+16

    float a_c = fminf(fmaxf(a_p[0], 0.f), 1.f);
    float am  = 1.f - a_c;
    float Pk  = wsP[cc];
    float Nk  = wsN[cc];
    float negM = -fmaxf(fabsf(Pk), fabsf(Nk));   // * DIST_MAX (=1, baked into bins)
    float lo = (float)cc * 0.0625f;
    float hi = lo + 0.0625f;

    int wbeg = e0 + wid * 128;
    int wend = wbeg + 128; if (wend > eEnd) wend = eEnd;

    if (!overflow) {
        for (int e = wbeg + esub; e < wend; e += 4) {
            float d  = dist[e];
            int   s  = send[e];
            float pe = padv[e];
            int   r  = recv[e];
            float* row = lds + (r - rFirst) * ROWS;
            const float* nsr = nodes + (s * K_TOT + cc);
            float ns0 = nsr[0], ns1 = nsr[16];
            const float* nrr = nodes + (r * K_TOT + cc);
            float nr0 = nrr[0], nr1 = nrr[16];
            float t0 = fmaf(a_c, nr0, -(am * ns0));
            float t1 = fmaf(a_c, nr1, -(am * ns1));
            float pd0 = t0 * t0, pd1 = t1 * t1;
            if ((d > lo) && (d < hi)) {
                unsafeAtomicAdd(row + cc, 1.f);
                unsafeAtomicAdd(row + cc + 16, pe * pd0);
            }
            float q = (d > 0.f) ? Pk : Nk;
            float p = __expf(fmaf(d, q, negM));
            unsafeAtomicAdd(row + cc + 32, p);
            unsafeAtomicAdd(row + cc + 48, p * (pe * pd1));
        }
    } else {
        for (int e = wbeg + esub; e < wend; e += 4) {
            float d  = dist[e];
            int   s  = send[e];
            float pe = padv[e];
            int   r  = recv[e];
            float* row = gacc + (size_t)r * 64;
            const float* nsr = nodes + (s * K_TOT + cc);
            float ns0 = nsr[0], ns1 = nsr[16];
            const float* nrr = nodes + (r * K_TOT + cc);
            float nr0 = nrr[0], nr1 = nrr[16];
            float t0 = fmaf(a_c, nr0, -(am * ns0));
            float t1 = fmaf(a_c, nr1, -(am * ns1));
            float pd0 = t0 * t0, pd1 = t1 * t1;
            if ((d > lo) && (d < hi)) {
                unsafeAtomicAdd(row + cc, 1.f);
                unsafeAtomicAdd(row + cc + 16, pe * pd0);
            }
            float q = (d > 0.f) ? Pk : Nk;
            float p = __expf(fmaf(d, q, negM));
            unsafeAtomicAdd(row + cc + 32, p);
            unsafeAtomicAdd(row + cc + 48, p * (pe * pd1));
        }
    }
    __syncthreads();

    if (!overflow) {
        // flush: interior receivers exclusive to this block -> store;
        // boundary (rFirst, rLast) shared with neighbor blocks -> atomic.
        int total = span * 64;
        for (int i = tid; i < total; i += 256) {
            int rl = i >> 6;
            int slot = i & 63;
            float v = lds[rl * ROWS + slot];
            int r = rFirst + rl;
            float* dst = gacc + (size_t)r * 64 + slot;
            if (r == rFirst || r == rLast) unsafeAtomicAdd(dst, v);
            else *dst = v;
        }
    }
}

// ------------------------------------------------------------------
// Node-parallel finalize + fused epilogue. Wave handles 2 nodes:
// p = lane>>5 selects node, c = lane&31 the channel.
// Fast path: read 64-float accum row (256B coalesced), finalize g.
// Generic path: full per-node recompute (powf + MLP + online softmax).
__global__ __launch_bounds__(256) void node_kernel(
        const float* __restrict__ nodes,
        const float* __restrict__ gacc,
        const float* __restrict__ wg_self,
        const float* __restrict__ wg_gath,
        const float* __restrict__ bg,
        float* __restrict__ out,
        int N,
        // generic-path inputs:
        const float* __restrict__ dist,
        const float* __restrict__ padv,
        const int*   __restrict__ send,
        const int*   __restrict__ rp,
        const float* __restrict__ w1,
        const float* __restrict__ b1,
        const float* __restrict__ w2,
        const float* __restrict__ a_p,
        const float* __restrict__ b_p,
        const int*   __restrict__ wsflag) {
    int wave = blockIdx.x * 4 + (threadIdx.x >> 6);
    int lane = threadIdx.x & 63;
    int n0 = wave * 2;
    if (n0 >= N) return;
    int p = lane >> 5;
    int c = lane & 31;
    int node = n0 + p;
    int nld = node < N ? node : N - 1;

    bool fastf = (*wsflag != 0) && (fabsf(b_p[0]) == 2.0f);
    float pre_g, pre_n;

    if (__builtin_amdgcn_readfirstlane((int)fastf)) {
        const float* row = gacc + (size_t)nld * 64;
        int s1 = (c < 16) ? c : c + 16;
        float v1 = row[s1];         // cnt or l
        float v2 = row[s1 + 16];    // si  or acc
        pre_g = (c < 16) ? v2 / (v1 + 1e-5f)
                         : ((v1 > 0.f) ? v2 / v1 : 0.f);
        pre_n = nodes[nld * K_TOT + c];
    } else {
        // -------- generic fallback: per-node recompute --------
        float a_c = fminf(fmaxf(a_p[0], 0.f), 1.f);
        float am  = 1.f - a_c;
        float bc  = fabsf(b_p[0]);
        int eg = lane >> 4, cc = lane & 15;
        float lo = (float)cc * 0.0625f;
        float hi = lo + 0.0625f;
        float gi0 = 0.f, gm0 = 0.f, gi1 = 0.f, gm1 = 0.f;
        for (int t = 0; t < 2; ++t) {
            int nn = n0 + t;
            float g_ind = 0.f, g_mlp = 0.f;
            if (nn < N) {
                const float* nrow = nodes + nn * K_TOT;
                float nr0 = nrow[cc], nr1 = nrow[cc + 16];
                float anr0 = a_c * nr0, anr1 = a_c * nr1;
                int e0 = rp[nn], eEnd = rp[nn + 1];
                float cnt = 0.f, si = 0.f, l = 0.f, acc = 0.f, m_on = -INFINITY;
                for (int i = e0 + eg; i < eEnd; i += 4) {
                    float d  = dist[i];
                    int   s  = send[i];
                    float pe = padv[i];
                    const float* nsr = nodes + (s * K_TOT + cc);
                    float ns0 = nsr[0], ns1 = nsr[16];
                    float t0 = fabsf(fmaf(-am, ns0, anr0));
                    float t1 = fabsf(fmaf(-am, ns1, anr1));
                    float pd0 = powf(t0, bc);
                    float pd1 = powf(t1, bc);
                    bool inb = (d > lo) && (d < hi);
                    cnt += inb ? 1.f : 0.f;
                    si  += inb ? pe * pd0 : 0.f;
                    float mlp = 0.f;   // b2 cancels in the softmax ratio
                    for (int j = 0; j < DHID; ++j) {
                        float h = fmaxf(fmaf(d, w1[j], b1[j]), 0.f);
                        mlp = fmaf(h, w2[j * K_MLP + cc], mlp);
                    }
                    float mn = fmaxf(m_on, mlp);
                    float al = (m_on == -INFINITY) ? 0.f : __expf(m_on - mn);
                    float pp = __expf(mlp - mn);
                    l   = fmaf(l, al, pp);
                    acc = fmaf(acc, al, pp * pe * pd1);
                    m_on = mn;
                }
#pragma unroll
                for (int off = 16; off <= 32; off <<= 1) {
                    cnt += __shfl_xor(cnt, off);
                    si  += __shfl_xor(si,  off);
                    float m2 = __shfl_xor(m_on, off), l2 = __shfl_xor(l, off), a2 = __shfl_xor(acc, off);
                    float mn = fmaxf(m_on, m2);
                    float f1 = (m_on == -INFINITY) ? 0.f : __expf(m_on - mn);
                    float f2 = (m2   == -INFINITY) ? 0.f : __expf(m2 - mn);
                    l   = l * f1 + l2 * f2;
                    acc = acc * f1 + a2 * f2;
                    m_on = mn;
                }
                g_ind = si / (cnt + 1e-5f);
                g_mlp = (l > 0.f) ? (acc / l) : 0.f;
            }
            if (t == 0) { gi0 = g_ind; gm0 = g_mlp; }
            else        { gi1 = g_ind; gm1 = g_mlp; }
        }
        int srcl = c & 15;
        float si0 = __shfl(gi0, srcl), si1 = __shfl(gi1, srcl);
        float sm0 = __shfl(gm0, srcl), sm1 = __shfl(gm1, srcl);
        float sgi = p ? si1 : si0;
        float sgm = p ? sm1 : sm0;
        pre_g = (c < 16) ? sgi : sgm;
        pre_n = nodes[nld * K_TOT + c];
    }

    // fused epilogue: out[node][c] = relu(sum_j nr_j*Ws[j][c] + g_j*Wg[j][c] + bg[c])
    float o = 0.f;
    int sbase = p << 5;
#pragma unroll
    for (int j = 0; j < 32; ++j) {
        float gj = __shfl(pre_g, sbase + j);
        float nj = __shfl(pre_n, sbase + j);
        o = fmaf(nj, wg_self[j * K_TOT + c], o);
        o = fmaf(gj, wg_gath[j * K_TOT + c], o);
    }
    if (node < N) out[node * K_TOT + c] = fmaxf(o + bg[c], 0.f);
}

// ------------------------------------------------------------------
// Fallback single-kernel path (R6, proven) for when ws_size is too small
// to hold the 25.6MB accumulator.
__global__ __launch_bounds__(256) void graph_kernel_fb(
        const float* __restrict__ nodes,
        const float* __restrict__ dist,
        const float* __restrict__ padv,
        const int*   __restrict__ send,
        const float* __restrict__ w1,
        const float* __restrict__ b1,
        const float* __restrict__ w2,
        const float* __restrict__ a_p,
        const float* __restrict__ b_p,
        const float* __restrict__ wg_self,
        const float* __restrict__ wg_gath,
        const float* __restrict__ bg,
        const float* __restrict__ wsP,
        const float* __restrict__ wsN,
        const int*   __restrict__ wsflag,
        const int*   __restrict__ rp,
        float* __restrict__ out,
        int N) {
    int wave = blockIdx.x * (blockDim.x >> 6) + (threadIdx.x >> 6);
    if (wave >= N) return;
    int n    = wave;
    int lane = threadIdx.x & 63;
    int eg   = lane >> 4;
    int cc   = lane & 15;

    float a_c = fminf(fmaxf(a_p[0], 0.f), 1.f);
    float am  = 1.f - a_c;
    float bc  = fabsf(b_p[0]);
    float Pk = wsP[cc];
    float Nk = wsN[cc];
    const float* nrow = nodes + n * K_TOT;
    float nr0 = nrow[cc];
    float nr1 = nrow[cc + 16];
    float anr0 = a_c * nr0, anr1 = a_c * nr1;
    int e0 = rp[n], eEnd = rp[n + 1];
    int len = eEnd - e0;
    float lo = (float)cc * 0.0625f;
    float hi = lo + 0.0625f;
    float cnt = 0.f, si = 0.f, l = 0.f, acc = 0.f;
    float g_ind, g_mlp;
    bool fastf = (*wsflag != 0) && (bc == 2.0f) && (len <= 64);

    if (__builtin_amdgcn_readfirstlane((int)fastf)) {
        if (len > 0) {
            int idx = lane < len ? lane : len - 1;
            float dm = fabsf(dist[e0 + idx]);
#pragma unroll
            for (int off = 32; off; off >>= 1) dm = fmaxf(dm, __shfl_xor(dm, off));
            float negM = -fmaxf(fabsf(Pk), fabsf(Nk)) * dm;
            int nG = (len + 3) >> 2;
            int last = len - 1;
            for (int g = 0; g < nG; ++g) {
                int i = (g << 2) + eg;
                bool valid = i < len;
                int ii = valid ? i : last;
                float d  = dist[e0 + ii];
                int   s  = send[e0 + ii];
                float pe = padv[e0 + ii];
                const float* nsr = nodes + (s * K_TOT + cc);
                float ns0 = nsr[0], ns1 = nsr[16];
                float t0 = fmaf(-am, ns0, anr0);
                float t1 = fmaf(-am, ns1, anr1);
                float pd0 = t0 * t0, pd1 = t1 * t1;
                bool inb = valid && (d > lo) && (d < hi);
                cnt += inb ? 1.f : 0.f;
                si   = inb ? fmaf(pe, pd0, si) : si;
                float q = (d > 0.f) ? Pk : Nk;
                float pp = __expf(fmaf(d, q, negM));
                pp = valid ? pp : 0.f;
                l += pp;
                acc = fmaf(pp, pe * pd1, acc);
            }
        }
#pragma unroll
        for (int off = 16; off <= 32; off <<= 1) {
            cnt += __shfl_xor(cnt, off);
            si  += __shfl_xor(si,  off);
            l   += __shfl_xor(l,   off);
            acc += __shfl_xor(acc, off);
        }
        g_ind = si / (cnt + 1e-5f);
        g_mlp = (l > 0.f) ? (acc / l) : 0.f;
    } else {
        float m_on = -INFINITY;
        for (int i = eg; i < len; i += 4) {
            int e = e0 + i;
            float d  = dist[e];
            int   s  = send[e];
            float pe = padv[e];
            const float* nsr = nodes + (s * K_TOT + cc);
            float ns0 = nsr[0], ns1 = nsr[16];
            float t0 = fabsf(fmaf(-am, ns0, anr0));
            float t1 = fabsf(fmaf(-am, ns1, anr1));
            float pd0 = powf(t0, bc), pd1 = powf(t1, bc);
            bool inb = (d > lo) && (d < hi);
            cnt += inb ? 1.f : 0.f;
            si  += inb ? pe * pd0 : 0.f;
            float mlp = 0.f;
            for (int j = 0; j < DHID; ++j) {
                float h = fmaxf(fmaf(d, w1[j], b1[j]), 0.f);
                mlp = fmaf(h, w2[j * K_MLP + cc], mlp);
            }
            float mn = fmaxf(m_on, mlp);
            float al = (m_on == -INFINITY) ? 0.f : __expf(m_on - mn);
            float pp = __expf(mlp - mn);
            l   = fmaf(l, al, pp);
            acc = fmaf(acc, al, pp * pe * pd1);
            m_on = mn;
        }
#pragma unroll
        for (int off = 16; off <= 32; off <<= 1) {
            cnt += __shfl_xor(cnt, off);
            si  += __shfl_xor(si,  off);
            float m2 = __shfl_xor(m_on, off), l2 = __shfl_xor(l, off), a2 = __shfl_xor(acc, off);
            float mn = fmaxf(m_on, m2);
            float f1 = (m_on == -INFINITY) ? 0.f : __expf(m_on - mn);
            float f2 = (m2   == -INFINITY) ? 0.f : __expf(m2 - mn);
            l   = l * f1 + l2 * f2;
            acc = acc * f1 + a2 * f2;
            m_on = mn;
        }
        g_ind = si / (cnt + 1e-5f);
        g_mlp = (l > 0.f) ? (acc / l) : 0.f;
    }

    int h  = lane >> 5;
    int oc = lane & 31;
    float pre_g = ((lane >> 4) & 1) ? g_mlp : g_ind;
    float pre_n = ((lane >> 4) & 1) ? nr1 : nr0;
    float o_s = 0.f, o_g = 0.f;
    int jbase = h * 16;
#pragma unroll
    for (int jj = 0; jj < 16; ++jj) {
        int j = jbase + jj;
        float gj = __shfl(pre_g, j);
        float nj = __shfl(pre_n, j);
        o_s = fmaf(nj, wg_self[j * K_TOT + oc], o_s);
        o_g = fmaf(gj, wg_gath[j * K_TOT + oc], o_g);
    }
    float o = o_s + o_g;
    o += __shfl_xor(o, 32);
    if (h == 0) {
        out[n * K_TOT + oc] = fmaxf(o + bg[oc], 0.f);
    }
}

// ------------------------------------------------------------------
extern "C" void kernel_launch(void* const* d_in, const int* in_sizes, int n_in,
                              void* d_out, int out_size, void* d_ws, size_t ws_size,
                              hipStream_t stream) {
    const float* nodes   = (const float*)d_in[0];
    const float* dist    = (const float*)d_in[1];
    const float* padv    = (const float*)d_in[2];
    const int*   recv    = (const int*)d_in[3];
    const int*   send    = (const int*)d_in[4];
    const float* w1      = (const float*)d_in[5];
    const float* b1      = (const float*)d_in[6];
    const float* w2      = (const float*)d_in[7];
    const float* a_p     = (const float*)d_in[9];
    const float* b_p     = (const float*)d_in[10];
    const float* wg_self = (const float*)d_in[11];
    const float* wg_gath = (const float*)d_in[12];
    const float* bg      = (const float*)d_in[13];
    float* out = (float*)d_out;

    int N = in_sizes[0] / K_TOT;
    int E = in_sizes[1];

    size_t gacc_elems = (size_t)N * 64;
    size_t need = (gacc_elems + 64 + (size_t)N + 1 + 64) * sizeof(float);

    if (ws_size >= need) {
        // ---- fast 4-dispatch path ----
        float* gacc   = (float*)d_ws;
        float* meta   = gacc + gacc_elems;
        float* wsP    = meta;
        float* wsN    = meta + 16;
        int*   wsflag = (int*)(meta + 32);
        int*   rp     = (int*)(meta + 64);

        prep_kernel<<<(N + 1 + 255) / 256, 256, 0, stream>>>(
            recv, E, N, w1, b1, w2, wsP, wsN, wsflag, rp);
        hipMemsetAsync(gacc, 0, gacc_elems * sizeof(float), stream);
        edge_kernel<<<(E + EB - 1) / EB, 256, 0, stream>>>(
            nodes, dist, padv, send, recv, a_p, b_p, wsP, wsN, wsflag, gacc, E);
        int nwaves = (N + 1) / 2;
        node_kernel<<<(nwaves + 3) / 4, 256, 0, stream>>>(
            nodes, gacc, wg_self, wg_gath, bg, out, N,
            dist, padv, send, rp, w1, b1, w2, a_p, b_p, wsflag);
    } else {
        // ---- fallback: proven single-kernel path (R6) ----
        float* wsf    = (float*)d_ws;
        float* wsP    = wsf;
        float* wsN    = wsf + 16;
        int*   wsflag = (int*)d_ws + 32;
        int*   rp     = (int*)d_ws + 64;

        prep_kernel<<<(N + 1 + 255) / 256, 256, 0, stream>>>(
            recv, E, N, w1, b1, w2, wsP, wsN, wsflag, rp);
        graph_kernel_fb<<<(N + 3) / 4, 256, 0, stream>>>(
            nodes, dist, padv, send, w1, b1, w2, a_p, b_p,
            wg_self, wg_gath, bg, wsP, wsN, wsflag, rp, out, N);
    }
}

// Round 9
// 213.999 us; speedup vs baseline: 2.0507x; 2.0478x over previous
//
#include <hip/hip_runtime.h>
#include <math.h>

#define K_TOT 32
#define K_IND 16
#define K_MLP 16
#define DHID  64

// ws layout (ints): P floats [0..16), N floats [16..32), flag @32,
// rp = ((int*)ws)+64, length N+1.

// Prep: block 0 wave 0 computes collapsed-MLP constants
//   P_k = sum_{j: w1_j>0} w1_j*w2[j][k], N_k = sum_{j: w1_j<0} w1_j*w2[j][k]
// and flag = (all b1 == 0). All threads t<=N: rp[t] = lower_bound(recv, t).
__global__ void prep_kernel(const int* __restrict__ recv, int E, int N,
                            const float* __restrict__ w1,
                            const float* __restrict__ b1,
                            const float* __restrict__ w2,
                            float* __restrict__ wsP,
                            float* __restrict__ wsN,
                            int* __restrict__ wsflag,
                            int* __restrict__ rp) {
    if (blockIdx.x == 0 && threadIdx.x < 64) {
        int t = threadIdx.x;
        if (t < K_MLP) {
            float P = 0.f, Nn = 0.f;
            for (int j = 0; j < DHID; ++j) {
                float w = w1[j];
                float v = w2[j * K_MLP + t];
                P  += fmaxf(w, 0.f) * v;
                Nn += fminf(w, 0.f) * v;
            }
            wsP[t] = P; wsN[t] = Nn;
        }
        bool nz = (b1[t] != 0.f);
        unsigned long long mask = __ballot(nz);
        if (t == 0) *wsflag = (mask == 0ull) ? 1 : 0;
    }
    int tid = blockIdx.x * blockDim.x + threadIdx.x;
    if (tid <= N) {
        int lo = 0, hi = E;
        while (lo < hi) {
            int mid = (lo + hi) >> 1;
            if (recv[mid] < tid) lo = mid + 1; else hi = mid;
        }
        rp[tid] = lo;
    }
}

// One wave = FOUR nodes. q = lane>>4 selects the node, cc = lane&15 the
// channel pair (indicator cc, mlp cc+16). Each iteration processes one edge
// per node (4 edges x 16 channels = 64 lanes). One accumulator slot per
// channel -> NO cross-slot merge. Fixed per-node cost (prologue, max|d|,
// finalize) amortized 4x vs the R6 wave-per-node design (whose profile
// decomposed to: loop 11us, fixed 37us, epilogue 28us of the 80us total).
// Fast path (all b1==0 && b==2): pd = t*t, bound-M softmax (M = max|q|*max|d|
// per node) -> pure sums. Slow generic path: 4 sequential R6-style passes.
__global__ __launch_bounds__(256) void graph4_kernel(
        const float* __restrict__ nodes,
        const float* __restrict__ dist,
        const float* __restrict__ padv,
        const int*   __restrict__ send,
        const float* __restrict__ w1,
        const float* __restrict__ b1,
        const float* __restrict__ w2,
        const float* __restrict__ a_p,
        const float* __restrict__ b_p,
        const float* __restrict__ wg_self,
        const float* __restrict__ wg_gath,
        const float* __restrict__ bg,
        const float* __restrict__ wsP,
        const float* __restrict__ wsN,
        const int*   __restrict__ wsflag,
        const int*   __restrict__ rp,
        float* __restrict__ out,
        int N) {
    int wave  = blockIdx.x * 4 + (threadIdx.x >> 6);
    int nbase = wave * 4;
    if (nbase >= N) return;
    int lane = threadIdx.x & 63;
    int q    = lane >> 4;     // node slot 0..3
    int cc   = lane & 15;     // channel pair index

    float a_c = fminf(fmaxf(a_p[0], 0.f), 1.f);
    float am  = 1.f - a_c;
    float bc  = fabsf(b_p[0]);
    float Pk  = wsP[cc];
    float Nk  = wsN[cc];

    int n  = nbase + q;
    int nl = (n < N) ? n : N - 1;
    int e0 = rp[nl], e1 = rp[nl + 1];
    int len = (n < N) ? (e1 - e0) : 0;
    int eb  = (len > 0) ? e0 : 0;     // safe base for masked loads

    float nr0 = nodes[nl * K_TOT + cc];
    float nr1 = nodes[nl * K_TOT + cc + 16];
    float anr0 = a_c * nr0, anr1 = a_c * nr1;

    float lo = (float)cc * 0.0625f;
    float hi = lo + 0.0625f;

    float cnt = 0.f, si = 0.f;     // indicator (channel cc) of node q
    float l = 0.f, acc = 0.f;      // softmax  (channel cc+16) of node q
    float g_ind, g_mlp;

    bool fastf = (*wsflag != 0) && (bc == 2.0f);

    if (__builtin_amdgcn_readfirstlane((int)fastf)) {
        // ---------------- FAST PATH ----------------
        // per-node max|d| (16-lane strided pre-pass + width-16 butterfly)
        float dm = 0.f;
        for (int i = cc; i < len; i += 16) dm = fmaxf(dm, fabsf(dist[e0 + i]));
        dm = fmaxf(dm, __shfl_xor(dm, 1, 16));
        dm = fmaxf(dm, __shfl_xor(dm, 2, 16));
        dm = fmaxf(dm, __shfl_xor(dm, 4, 16));
        dm = fmaxf(dm, __shfl_xor(dm, 8, 16));
        float negM = -fmaxf(fabsf(Pk), fabsf(Nk)) * dm;

        // uniform trip count = max len over the 4 node slots
        int T = len;
        { int t2 = __shfl_xor(T, 16); T = T > t2 ? T : t2; }
        { int t2 = __shfl_xor(T, 32); T = T > t2 ? T : t2; }
        int last = (len > 0) ? (len - 1) : 0;

#define IT_BODY(I)                                                        \
        {                                                                 \
            int  ii = (I) < last ? (I) : last;                            \
            bool valid = (I) < len;                                       \
            int  idx = eb + ii;                                           \
            float d  = dist[idx];                                         \
            int   s  = send[idx];                                         \
            float pe = padv[idx];                                         \
            const float* nsr = nodes + (s * K_TOT + cc);                  \
            float ns0 = nsr[0], ns1 = nsr[16];                            \
            float t0 = fmaf(-am, ns0, anr0);                              \
            float t1 = fmaf(-am, ns1, anr1);                              \
            float pd0 = t0 * t0, pd1 = t1 * t1;                           \
            bool inb = valid && (d > lo) && (d < hi);                     \
            cnt += inb ? 1.f : 0.f;                                       \
            si   = inb ? fmaf(pe, pd0, si) : si;                          \
            float qq = (d > 0.f) ? Pk : Nk;                               \
            float p = __expf(fmaf(d, qq, negM));                          \
            p = valid ? p : 0.f;                                          \
            l += p;                                                       \
            acc = fmaf(p, pe * pd1, acc);                                 \
        }
        int i = 0;
        for (; i + 2 <= T; i += 2) { IT_BODY(i) IT_BODY(i + 1) }
        if (i < T) { IT_BODY(i) }
#undef IT_BODY

        g_ind = si / (cnt + 1e-5f);
        g_mlp = (l > 0.f) ? (acc / l) : 0.f;
    } else {
        // ---------------- SLOW GENERIC PATH ----------------
        // process the 4 nodes sequentially with the full 64-lane layout
        // (eg = lane>>4 edge slots), select each result into the (q,cc) lane.
        g_ind = 0.f; g_mlp = 0.f;
        int eg = lane >> 4;
        for (int t = 0; t < 4; ++t) {
            int nn = nbase + t;
            float gi = 0.f, gm = 0.f;
            if (nn < N) {
                const float* nrow = nodes + nn * K_TOT;
                float xr0 = nrow[cc], xr1 = nrow[cc + 16];
                float ax0 = a_c * xr0, ax1 = a_c * xr1;
                int ee0 = rp[nn], ee1 = rp[nn + 1];
                float tc = 0.f, ts = 0.f, tl = 0.f, ta = 0.f, m_on = -INFINITY;
                for (int i2 = ee0 + eg; i2 < ee1; i2 += 4) {
                    float d  = dist[i2];
                    int   s  = send[i2];
                    float pe = padv[i2];
                    const float* nsr = nodes + (s * K_TOT + cc);
                    float ns0 = nsr[0], ns1 = nsr[16];
                    float t0 = fabsf(fmaf(-am, ns0, ax0));
                    float t1 = fabsf(fmaf(-am, ns1, ax1));
                    float pd0 = powf(t0, bc), pd1 = powf(t1, bc);
                    bool inb = (d > lo) && (d < hi);
                    tc += inb ? 1.f : 0.f;
                    ts += inb ? pe * pd0 : 0.f;
                    float mlp = 0.f;   // b2 cancels in the softmax ratio
                    for (int j = 0; j < DHID; ++j) {
                        float h = fmaxf(fmaf(d, w1[j], b1[j]), 0.f);
                        mlp = fmaf(h, w2[j * K_MLP + cc], mlp);
                    }
                    float mn = fmaxf(m_on, mlp);
                    float al = (m_on == -INFINITY) ? 0.f : __expf(m_on - mn);
                    float pp = __expf(mlp - mn);
                    tl = fmaf(tl, al, pp);
                    ta = fmaf(ta, al, pp * pe * pd1);
                    m_on = mn;
                }
#pragma unroll
                for (int off = 16; off <= 32; off <<= 1) {
                    tc += __shfl_xor(tc, off);
                    ts += __shfl_xor(ts, off);
                    float m2 = __shfl_xor(m_on, off), l2 = __shfl_xor(tl, off), a2 = __shfl_xor(ta, off);
                    float mn = fmaxf(m_on, m2);
                    float f1 = (m_on == -INFINITY) ? 0.f : __expf(m_on - mn);
                    float f2 = (m2   == -INFINITY) ? 0.f : __expf(m2 - mn);
                    tl = tl * f1 + l2 * f2;
                    ta = ta * f1 + a2 * f2;
                    m_on = mn;
                }
                gi = ts / (tc + 1e-5f);
                gm = (tl > 0.f) ? (ta / tl) : 0.f;
            }
            if (q == t) { g_ind = gi; g_mlp = gm; }
        }
    }

    // ---- fused epilogue: 2 passes, each handling 2 nodes ----
    // pass p: half = lane>>5 selects node nbase+2p+half, oc = lane&31.
    // lane (half*32 + j) holds channel j of node (2p+half) in pre_g/pre_n.
    int half = lane >> 5;
    int oc   = lane & 31;
    int jb   = half << 5;
#pragma unroll
    for (int pass = 0; pass < 2; ++pass) {
        int tnode = nbase + 2 * pass + half;
        int src = (2 * pass + half) * 16 + (oc & 15);
        float sgi = __shfl(g_ind, src);
        float sgm = __shfl(g_mlp, src);
        float sn0 = __shfl(nr0, src);
        float sn1 = __shfl(nr1, src);
        float pre_g = (oc < 16) ? sgi : sgm;
        float pre_n = (oc < 16) ? sn0 : sn1;
        float o = 0.f;
#pragma unroll
        for (int j = 0; j < 32; ++j) {
            float gj = __shfl(pre_g, jb + j);
            float nj = __shfl(pre_n, jb + j);
            o = fmaf(nj, wg_self[j * K_TOT + oc], o);
            o = fmaf(gj, wg_gath[j * K_TOT + oc], o);
        }
        if (tnode < N) out[tnode * K_TOT + oc] = fmaxf(o + bg[oc], 0.f);
    }
}

extern "C" void kernel_launch(void* const* d_in, const int* in_sizes, int n_in,
                              void* d_out, int out_size, void* d_ws, size_t ws_size,
                              hipStream_t stream) {
    const float* nodes   = (const float*)d_in[0];
    const float* dist    = (const float*)d_in[1];
    const float* padv    = (const float*)d_in[2];
    const int*   recv    = (const int*)d_in[3];
    const int*   send    = (const int*)d_in[4];
    const float* w1      = (const float*)d_in[5];
    const float* b1      = (const float*)d_in[6];
    const float* w2      = (const float*)d_in[7];
    const float* a_p     = (const float*)d_in[9];
    const float* b_p     = (const float*)d_in[10];
    const float* wg_self = (const float*)d_in[11];
    const float* wg_gath = (const float*)d_in[12];
    const float* bg      = (const float*)d_in[13];
    float* out = (float*)d_out;

    int N = in_sizes[0] / K_TOT;
    int E = in_sizes[1];

    float* wsf    = (float*)d_ws;
    float* wsP    = wsf;
    float* wsN    = wsf + 16;
    int*   wsflag = (int*)d_ws + 32;
    int*   rp     = (int*)d_ws + 64;

    prep_kernel<<<(N + 1 + 255) / 256, 256, 0, stream>>>(recv, E, N, w1, b1, w2,
                                                         wsP, wsN, wsflag, rp);
    int nwaves = (N + 3) / 4;
    graph4_kernel<<<(nwaves + 3) / 4, 256, 0, stream>>>(
        nodes, dist, padv, send, w1, b1, w2, a_p, b_p,
        wg_self, wg_gath, bg, wsP, wsN, wsflag, rp, out, N);
}